// Round 10
// baseline (37.540 us; speedup 1.0000x reference)
//
#include <hip/hip_runtime.h>
#include <cstddef>
#include <cstdint>

#define BDIM 4
#define HH   64
#define WW   64
#define HWSZ 4096
#define CIN  256

typedef __attribute__((ext_vector_type(4))) float f32x4;
typedef _Float16 f16x4_t __attribute__((ext_vector_type(4)));
typedef _Float16 f16x8_t __attribute__((ext_vector_type(8)));

__device__ __forceinline__ void lds_load16(const void* g, void* l) {
    __builtin_amdgcn_global_load_lds(
        (const __attribute__((address_space(1))) unsigned int*)g,
        (__attribute__((address_space(3))) unsigned int*)l, 16, 0, 0);
}

// One fully-fused kernel: per block = (batch b, 4-row tile ht, group g).
// Phase A: GEMM [q;k](128ch) x tile(384 halo px) -> swizzled LDS fp16
// Phase A2: logits + softmax (2 threads/px, 32ch each, shfl_xor(32))
// Phase B: GEMM v(64ch) x tile -> vlds (overlays klds)
// Phase B2: PV + direct global out write. No qkv HBM round-trip.
__global__ __launch_bounds__(512, 2) void fused_kernel(
    const float* __restrict__ x,
    const float* __restrict__ wq, const float* __restrict__ bq,
    const float* __restrict__ wk, const float* __restrict__ bk,
    const float* __restrict__ wv, const float* __restrict__ bv,
    float* __restrict__ out)
{
    __shared__ float    As[128 * 32];    // 16 KB  W stage (Av reuses first 8 KB)
    __shared__ float    Bs[32 * 384];    // 48 KB  x stage (fp32)
    __shared__ _Float16 qlds[256 * 64];  // 32 KB  q, inner px, swizzled
    __shared__ _Float16 klds[384 * 64];  // 48 KB  k halo px, swizzled (vlds overlays)

    const int t   = threadIdx.x;
    const int bx0 = blockIdx.x;
    const int bx  = (bx0 & 7) * 32 + (bx0 >> 3);   // XCD swizzle (256 = 8*32)
    const int g   = bx & 3;
    const int ht  = (bx >> 2) & 15;
    const int b   = bx >> 6;
    const int h0  = ht * 4;

    const int l    = t & 63;
    const int wid  = t >> 6;          // 0..7
    const int lrow = l & 15;
    const int grp  = l >> 4;          // 0..3
    const int grp4 = grp * 4;
    const int wmA  = wid >> 2;        // phase A: 0=q rows, 1=k rows
    const int wnA  = wid & 3;         // phase A: px quarter

    const float* xb = x + (size_t)b * CIN * HWSZ;

    // ---- staging source pointers ----
    // A side: U = i*512 + t ; m = U>>3, kb = U&7, src col-block = kb^(m&7)
    const int ms  = t >> 3;                       // 0..63
    const int kbs = ((t & 7) ^ (ms & 7)) * 4;     // float offset within 32-k chunk
    const float* aSrcQ = wq + (size_t)(g * 64 + ms) * CIN + kbs;
    const float* aSrcK = wk + (size_t)(g * 64 + ms) * CIN + kbs;
    const float* aSrcV = wv + (size_t)(g * 64 + ms) * CIN + kbs;

    // B side: U = i*512 + t in [0,3072): k = U/96, rem = U%96, r = rem>>4,
    // u0 = rem&15; src col-unit = u0 ^ ((k>>3)<<2); src row clamped halo row.
    const float* bSrc[6];
    #pragma unroll
    for (int i = 0; i < 6; ++i) {
        const unsigned U = i * 512 + t;
        const unsigned k = U / 96u;
        const unsigned rem = U - k * 96u;
        const int r  = (int)(rem >> 4);
        const int u0 = (int)(rem & 15);
        int srow = h0 - 1 + r;
        srow = srow < 0 ? 0 : (srow > 63 ? 63 : srow);
        const int cu = u0 ^ (((int)(k >> 3)) << 2);
        bSrc[i] = xb + (size_t)k * HWSZ + srow * 64 + cu * 4;
    }

    // =================== Phase A: q+k GEMM (128 x 384) ===================
    const float* biasA = wmA ? bk : bq;
    f32x4 accA[4][6];
    #pragma unroll
    for (int mi = 0; mi < 4; ++mi) {
        const f32x4 bb = *(const f32x4*)&biasA[g * 64 + mi * 16 + grp4];
        #pragma unroll
        for (int ni = 0; ni < 6; ++ni) accA[mi][ni] = bb;
    }

    for (int kt = 0; kt < 8; ++kt) {
        const size_t ko = (size_t)kt * 32;
        lds_load16(aSrcQ + ko, As + t * 4);
        lds_load16(aSrcK + ko, As + 2048 + t * 4);
        #pragma unroll
        for (int i = 0; i < 6; ++i)
            lds_load16(bSrc[i] + ko * HWSZ, Bs + (i * 512 + t) * 4);
        __syncthreads();

        f16x8_t af[4];
        #pragma unroll
        for (int mi = 0; mi < 4; ++mi) {
            const int m = wmA * 64 + mi * 16 + lrow;
            const int s = m & 7;
            const f32x4 a0 = *(const f32x4*)&As[m * 32 + ((2 * grp) ^ s) * 4];
            const f32x4 a1 = *(const f32x4*)&As[m * 32 + ((2 * grp + 1) ^ s) * 4];
            f16x8_t f;
            #pragma unroll
            for (int j = 0; j < 4; ++j) { f[j] = (_Float16)a0[j]; f[4 + j] = (_Float16)a1[j]; }
            af[mi] = f;
        }
        f16x8_t bf[6];
        #pragma unroll
        for (int ni = 0; ni < 6; ++ni) {
            const int px  = wnA * 96 + ni * 16 + lrow;
            const int fo  = ((px >> 2) ^ (grp << 2)) * 4 + (px & 3);
            f16x8_t f;
            #pragma unroll
            for (int j = 0; j < 8; ++j) f[j] = (_Float16)Bs[(grp * 8 + j) * 384 + fo];
            bf[ni] = f;
        }
        #pragma unroll
        for (int mi = 0; mi < 4; ++mi)
            #pragma unroll
            for (int ni = 0; ni < 6; ++ni)
                accA[mi][ni] = __builtin_amdgcn_mfma_f32_16x16x32_f16(
                    af[mi], bf[ni], accA[mi][ni], 0, 0, 0);
        __syncthreads();
    }

    // epilogue: q (inner px only) / k (all halo px) -> swizzled LDS fp16
    #pragma unroll
    for (int ni = 0; ni < 6; ++ni) {
        const int px = wnA * 96 + ni * 16 + lrow;
        const int spx = (wmA == 0) ? (px - 64) : px;
        const bool ok = (wmA == 0) ? (spx >= 0 && spx < 256) : true;
        _Float16* dl = (wmA == 0) ? qlds : klds;
        #pragma unroll
        for (int mi = 0; mi < 4; ++mi) {
            if (ok) {
                const int cb  = mi * 2 + (grp >> 1);
                const int off = (grp & 1) * 4;
                f16x4_t hv;
                #pragma unroll
                for (int j = 0; j < 4; ++j) hv[j] = (_Float16)accA[mi][ni][j];
                *(f16x4_t*)&dl[spx * 64 + ((cb ^ (spx & 7)) * 8) + off] = hv;
            }
        }
    }
    __syncthreads();

    // =================== Phase A2: logits + softmax ===================
    const int pxi  = wid * 32 + (l & 31);   // inner px 0..255
    const int chh  = l >> 5;                // 0/1 channel half
    const int hq   = h0 + (pxi >> 6);
    const int wcol = pxi & 63;

    float qf[32];
    #pragma unroll
    for (int jj = 0; jj < 4; ++jj) {
        const int cb = chh * 4 + jj;
        const f16x8_t qv = *(const f16x8_t*)&qlds[pxi * 64 + ((cb ^ (pxi & 7)) * 8)];
        #pragma unroll
        for (int e = 0; e < 8; ++e) qf[jj * 8 + e] = (float)qv[e];
    }

    float lg[9];
    #pragma unroll
    for (int p = 0; p < 9; ++p) {
        const int dh = p / 3 - 1, dw = p % 3 - 1;
        const int h2 = hq + dh, w2 = wcol + dw;
        float part = 0.f;
        if (h2 >= 0 && h2 < HH && w2 >= 0 && w2 < WW) {
            const int hpx = pxi + 64 + dh * 64 + dw;
            #pragma unroll
            for (int jj = 0; jj < 4; ++jj) {
                const int cb = chh * 4 + jj;
                const f16x8_t kv = *(const f16x8_t*)&klds[hpx * 64 + ((cb ^ (hpx & 7)) * 8)];
                #pragma unroll
                for (int e = 0; e < 8; ++e) part += qf[jj * 8 + e] * (float)kv[e];
            }
        }
        part += __shfl_xor(part, 32, 64);
        lg[p] = part;
    }

    float mx = lg[0];
    #pragma unroll
    for (int p = 1; p < 9; ++p) mx = fmaxf(mx, lg[p]);
    float a[9];
    float sum = 0.f;
    #pragma unroll
    for (int p = 0; p < 9; ++p) { a[p] = __expf(lg[p] - mx); sum += a[p]; }
    const float inv = 1.f / sum;
    #pragma unroll
    for (int p = 0; p < 9; ++p) a[p] *= inv;

    // =================== Phase B: v GEMM (64 x 384) ===================
    f32x4 accB[4][3];
    #pragma unroll
    for (int mi = 0; mi < 4; ++mi) {
        const f32x4 bb = *(const f32x4*)&bv[g * 64 + mi * 16 + grp4];
        #pragma unroll
        for (int ni = 0; ni < 3; ++ni) accB[mi][ni] = bb;
    }

    for (int kt = 0; kt < 8; ++kt) {
        const size_t ko = (size_t)kt * 32;
        lds_load16(aSrcV + ko, As + t * 4);
        #pragma unroll
        for (int i = 0; i < 6; ++i)
            lds_load16(bSrc[i] + ko * HWSZ, Bs + (i * 512 + t) * 4);
        __syncthreads();

        f16x8_t af[4];
        #pragma unroll
        for (int mi = 0; mi < 4; ++mi) {
            const int m = mi * 16 + lrow;
            const int s = m & 7;
            const f32x4 a0 = *(const f32x4*)&As[m * 32 + ((2 * grp) ^ s) * 4];
            const f32x4 a1 = *(const f32x4*)&As[m * 32 + ((2 * grp + 1) ^ s) * 4];
            f16x8_t f;
            #pragma unroll
            for (int j = 0; j < 4; ++j) { f[j] = (_Float16)a0[j]; f[4 + j] = (_Float16)a1[j]; }
            af[mi] = f;
        }
        f16x8_t bf[3];
        #pragma unroll
        for (int ni = 0; ni < 3; ++ni) {
            const int px = wid * 48 + ni * 16 + lrow;
            const int fo = ((px >> 2) ^ (grp << 2)) * 4 + (px & 3);
            f16x8_t f;
            #pragma unroll
            for (int j = 0; j < 8; ++j) f[j] = (_Float16)Bs[(grp * 8 + j) * 384 + fo];
            bf[ni] = f;
        }
        #pragma unroll
        for (int mi = 0; mi < 4; ++mi)
            #pragma unroll
            for (int ni = 0; ni < 3; ++ni)
                accB[mi][ni] = __builtin_amdgcn_mfma_f32_16x16x32_f16(
                    af[mi], bf[ni], accB[mi][ni], 0, 0, 0);
        __syncthreads();
    }

    // epilogue: v -> vlds (overlays klds; all logits done before first B barrier)
    #pragma unroll
    for (int ni = 0; ni < 3; ++ni) {
        const int px = wid * 48 + ni * 16 + lrow;
        #pragma unroll
        for (int mi = 0; mi < 4; ++mi) {
            const int cb  = mi * 2 + (grp >> 1);
            const int off = (grp & 1) * 4;
            f16x4_t hv;
            #pragma unroll
            for (int j = 0; j < 4; ++j) hv[j] = (_Float16)accB[mi][ni][j];
            *(f16x4_t*)&klds[px * 64 + ((cb ^ (px & 7)) * 8) + off] = hv;
        }
    }
    __syncthreads();

    // =================== Phase B2: PV + out write ===================
    float oacc[32];
    #pragma unroll
    for (int c = 0; c < 32; ++c) oacc[c] = 0.f;
    #pragma unroll
    for (int p = 0; p < 9; ++p) {
        const int dh = p / 3 - 1, dw = p % 3 - 1;
        const int h2 = hq + dh, w2 = wcol + dw;
        if (h2 < 0 || h2 >= HH || w2 < 0 || w2 >= WW) continue;
        const float ap = a[p];
        const int hpx = pxi + 64 + dh * 64 + dw;
        #pragma unroll
        for (int jj = 0; jj < 4; ++jj) {
            const int cb = chh * 4 + jj;
            const f16x8_t vv = *(const f16x8_t*)&klds[hpx * 64 + ((cb ^ (hpx & 7)) * 8)];
            #pragma unroll
            for (int e = 0; e < 8; ++e) oacc[jj * 8 + e] += ap * (float)vv[e];
        }
    }

    float* ob = out + ((size_t)(b * 256 + g * 64 + chh * 32)) * HWSZ + ht * 256 + pxi;
    #pragma unroll
    for (int c = 0; c < 32; ++c) ob[(size_t)c * HWSZ] = oacc[c];
}

extern "C" void kernel_launch(void* const* d_in, const int* in_sizes, int n_in,
                              void* d_out, int out_size, void* d_ws, size_t ws_size,
                              hipStream_t stream) {
    const float* x  = (const float*)d_in[0];
    const float* wq = (const float*)d_in[1];
    const float* bq = (const float*)d_in[2];
    const float* wk = (const float*)d_in[3];
    const float* bk = (const float*)d_in[4];
    const float* wv = (const float*)d_in[5];
    const float* bv = (const float*)d_in[6];
    float* out = (float*)d_out;

    fused_kernel<<<dim3(256), 512, 0, stream>>>(x, wq, bq, wk, bk, wv, bv, out);
}